// Round 1
// baseline (855.040 us; speedup 1.0000x reference)
//
#include <hip/hip_runtime.h>
#include <hip/hip_bf16.h>

#define N_NODES 50000
#define N_EDGES 800000
#define E_TOT   (N_EDGES + N_NODES)   // 850000, self-loops appended at end

// ---------------------------------------------------------------- CSR build
__global__ void k_hist(const int* __restrict__ ei, int* __restrict__ cnt) {
  int e = blockIdx.x * blockDim.x + threadIdx.x;
  if (e >= E_TOT) return;
  int d = (e < N_EDGES) ? ei[N_EDGES + e] : (e - N_EDGES);
  atomicAdd(&cnt[d], 1);
}

__global__ __launch_bounds__(1024) void k_scan(const int* __restrict__ cnt,
                                               int* __restrict__ rowptr,
                                               int* __restrict__ cursor) {
  __shared__ int sums[1024];
  const int STRIP = (N_NODES + 1023) / 1024;  // 49
  int t = threadIdx.x;
  int lo = t * STRIP;
  int hi = lo + STRIP; if (hi > N_NODES) hi = N_NODES;
  if (lo > N_NODES) lo = N_NODES;
  int s = 0;
  for (int i = lo; i < hi; ++i) s += cnt[i];
  sums[t] = s;
  __syncthreads();
  for (int off = 1; off < 1024; off <<= 1) {
    int v = (t >= off) ? sums[t - off] : 0;
    __syncthreads();
    sums[t] += v;
    __syncthreads();
  }
  int run = sums[t] - s;  // exclusive prefix of strip sums
  for (int i = lo; i < hi; ++i) {
    rowptr[i] = run; cursor[i] = run;
    run += cnt[i];
  }
  if (t == 1023) rowptr[N_NODES] = sums[1023];
}

__global__ void k_scatter(const int* __restrict__ ei, int* __restrict__ cursor,
                          int* __restrict__ csr) {
  int e = blockIdx.x * blockDim.x + threadIdx.x;
  if (e >= E_TOT) return;
  int s, d;
  if (e < N_EDGES) { s = ei[e]; d = ei[N_EDGES + e]; }
  else             { s = d = e - N_EDGES; }
  int pos = atomicAdd(&cursor[d], 1);
  csr[pos] = s;
}

// ---------------------------------------------------------------- fp32 GEMM
// C[M,Nn] = A[M,Kd] @ B[Kd,Nn].  64x64 tile, 4x4 per-thread, K-chunk 16.
__global__ __launch_bounds__(256) void k_gemm(const float* __restrict__ A,
                                              const float* __restrict__ B,
                                              float* __restrict__ C,
                                              int M, int Nn, int Kd) {
  __shared__ float As[16][64];
  __shared__ float Bs[16][64];
  int row0 = blockIdx.x * 64;
  int n0   = blockIdx.y * 64;
  int t = threadIdx.x;
  int tx = t & 15, ty = t >> 4;
  int r0 = ty * 4, c0 = tx * 4;
  float acc[4][4] = {};
  for (int kc = 0; kc < Kd; kc += 16) {
    {  // A tile: thread -> (row = t/4, k-quad = (t%3)*4)
      int r = t >> 2, kq = (t & 3) * 4;
      int gr = row0 + r;
      float4 a4 = make_float4(0.f, 0.f, 0.f, 0.f);
      if (gr < M) a4 = *(const float4*)&A[(size_t)gr * Kd + kc + kq];
      As[kq + 0][r] = a4.x; As[kq + 1][r] = a4.y;
      As[kq + 2][r] = a4.z; As[kq + 3][r] = a4.w;
    }
    {  // B tile: 16 rows x 64 cols
      int c = t & 63, kr = t >> 6;  // kr in 0..3
      #pragma unroll
      for (int p = 0; p < 4; ++p)
        Bs[kr + p * 4][c] = B[(size_t)(kc + kr + p * 4) * Nn + n0 + c];
    }
    __syncthreads();
    #pragma unroll
    for (int kk = 0; kk < 16; ++kk) {
      float4 a4 = *(const float4*)&As[kk][r0];
      float4 b4 = *(const float4*)&Bs[kk][c0];
      float av[4] = {a4.x, a4.y, a4.z, a4.w};
      float bv[4] = {b4.x, b4.y, b4.z, b4.w};
      #pragma unroll
      for (int i = 0; i < 4; ++i)
        #pragma unroll
        for (int j = 0; j < 4; ++j)
          acc[i][j] += av[i] * bv[j];
    }
    __syncthreads();
  }
  #pragma unroll
  for (int i = 0; i < 4; ++i) {
    int gr = row0 + r0 + i;
    if (gr < M)
      #pragma unroll
      for (int j = 0; j < 4; ++j)
        C[(size_t)gr * Nn + n0 + c0 + j] = acc[i][j];
  }
}

// ------------------------------------------------- per-node attention coeffs
template <int H>
__global__ void k_att(const float* __restrict__ h, const float* __restrict__ atts,
                      const float* __restrict__ attd,
                      float* __restrict__ aS, float* __restrict__ aD) {
  int wid  = (int)((blockIdx.x * (size_t)blockDim.x + threadIdx.x) >> 6);
  int lane = threadIdx.x & 63;
  if (wid >= N_NODES) return;
  #pragma unroll
  for (int hh = 0; hh < H; ++hh) {
    float v  = h[(size_t)wid * (H * 64) + hh * 64 + lane];
    float vs = v * atts[hh * 64 + lane];
    float vd = v * attd[hh * 64 + lane];
    #pragma unroll
    for (int off = 32; off; off >>= 1) {
      vs += __shfl_down(vs, off);
      vd += __shfl_down(vd, off);
    }
    if (lane == 0) { aS[wid * H + hh] = vs; aD[wid * H + hh] = vd; }
  }
}

// ------------------------------------------ edge-softmax + aggregate (wave/(n,h))
template <int H, bool ELU>
__global__ void k_aggr(const int* __restrict__ rowptr, const int* __restrict__ csr,
                       const float* __restrict__ h, const float* __restrict__ aS,
                       const float* __restrict__ aD, const float* __restrict__ bias,
                       float* __restrict__ out) {
  int wid  = (int)((blockIdx.x * (size_t)blockDim.x + threadIdx.x) >> 6);
  int lane = threadIdx.x & 63;
  if (wid >= N_NODES * H) return;
  int n = wid / H, hh = wid - n * H;
  const int stride = H * 64;
  float adv = aD[n * H + hh];
  float m = -1e30f, s = 0.f, acc = 0.f;
  int lo = rowptr[n], hi = rowptr[n + 1];
  for (int k = lo; k < hi; ++k) {
    int j = csr[k];
    float e = aS[j * H + hh] + adv;
    e = e > 0.f ? e : 0.2f * e;
    float hv = h[(size_t)j * stride + hh * 64 + lane];
    if (e > m) {  // wave-uniform branch
      float sc = __expf(m - e);
      s   = s * sc + 1.f;
      acc = acc * sc + hv;
      m = e;
    } else {
      float w = __expf(e - m);
      s += w; acc += w * hv;
    }
  }
  float v = acc / s + bias[hh * 64 + lane];
  if (ELU) v = v > 0.f ? v : __expf(v) - 1.f;
  out[(size_t)n * stride + hh * 64 + lane] = v;
}

// --------------------------------------------------------- layer-3 (C=2, H=1)
__global__ void k_proj3(const float* __restrict__ hin, const float* __restrict__ W3,
                        const float* __restrict__ s3, const float* __restrict__ d3,
                        float* __restrict__ h3, float* __restrict__ a3s,
                        float* __restrict__ a3d) {
  int n = blockIdx.x * blockDim.x + threadIdx.x;
  if (n >= N_NODES) return;
  float a0 = 0.f, a1 = 0.f;
  const float4* hp = (const float4*)(hin + (size_t)n * 128);
  #pragma unroll
  for (int q = 0; q < 32; ++q) {
    float4 v = hp[q];
    const float* w = W3 + q * 8;
    a0 += v.x * w[0] + v.y * w[2] + v.z * w[4] + v.w * w[6];
    a1 += v.x * w[1] + v.y * w[3] + v.z * w[5] + v.w * w[7];
  }
  h3[(size_t)n * 2]     = a0;
  h3[(size_t)n * 2 + 1] = a1;
  a3s[n] = a0 * s3[0] + a1 * s3[1];
  a3d[n] = a0 * d3[0] + a1 * d3[1];
}

__global__ void k_aggr3(const int* __restrict__ rowptr, const int* __restrict__ csr,
                        const float* __restrict__ h3, const float* __restrict__ a3s,
                        const float* __restrict__ a3d, const float* __restrict__ b3,
                        float* __restrict__ out) {
  int n = blockIdx.x * blockDim.x + threadIdx.x;
  if (n >= N_NODES) return;
  float adv = a3d[n];
  float m = -1e30f, s = 0.f, acc0 = 0.f, acc1 = 0.f;
  int lo = rowptr[n], hi = rowptr[n + 1];
  for (int k = lo; k < hi; ++k) {
    int j = csr[k];
    float e = a3s[j] + adv;
    e = e > 0.f ? e : 0.2f * e;
    float h0 = h3[(size_t)j * 2], h1 = h3[(size_t)j * 2 + 1];
    if (e > m) {
      float sc = __expf(m - e);
      s = s * sc + 1.f; acc0 = acc0 * sc + h0; acc1 = acc1 * sc + h1;
      m = e;
    } else {
      float w = __expf(e - m);
      s += w; acc0 += w * h0; acc1 += w * h1;
    }
  }
  float o0 = acc0 / s + b3[0];
  float o1 = acc1 / s + b3[1];
  float mx = fmaxf(o0, o1);
  float l  = logf(__expf(o0 - mx) + __expf(o1 - mx));
  out[(size_t)n * 2]     = o0 - mx - l;
  out[(size_t)n * 2 + 1] = o1 - mx - l;
}

// ---------------------------------------------------------------- launcher
extern "C" void kernel_launch(void* const* d_in, const int* in_sizes, int n_in,
                              void* d_out, int out_size, void* d_ws, size_t ws_size,
                              hipStream_t stream) {
  const float* x   = (const float*)d_in[0];
  const int*   ei  = (const int*)d_in[1];
  const float* W1  = (const float*)d_in[2];
  const float* as1 = (const float*)d_in[3];
  const float* ad1 = (const float*)d_in[4];
  const float* b1  = (const float*)d_in[5];
  const float* W2  = (const float*)d_in[6];
  const float* as2 = (const float*)d_in[7];
  const float* ad2 = (const float*)d_in[8];
  const float* b2  = (const float*)d_in[9];
  const float* W3  = (const float*)d_in[10];
  const float* as3 = (const float*)d_in[11];
  const float* ad3 = (const float*)d_in[12];
  const float* b3  = (const float*)d_in[13];
  float* out = (float*)d_out;

  char* p = (char*)d_ws;
  auto alloc = [&](size_t bytes) -> char* {
    char* r = p; p += (bytes + 255) & ~(size_t)255; return r;
  };
  int*   cnt    = (int*)alloc((size_t)N_NODES * 4);
  int*   rowptr = (int*)alloc((size_t)(N_NODES + 1) * 4);
  int*   cursor = (int*)alloc((size_t)N_NODES * 4);
  int*   csr    = (int*)alloc((size_t)E_TOT * 4);
  float* aS     = (float*)alloc((size_t)N_NODES * 4 * 4);
  float* aD     = (float*)alloc((size_t)N_NODES * 4 * 4);
  float* h3     = (float*)alloc((size_t)N_NODES * 2 * 4);
  float* a3s    = (float*)alloc((size_t)N_NODES * 4);
  float* a3d    = (float*)alloc((size_t)N_NODES * 4);
  float* hA     = (float*)alloc((size_t)N_NODES * 256 * 4);
  float* hB     = (float*)alloc((size_t)N_NODES * 256 * 4);

  // CSR (reused by all three layers)
  hipMemsetAsync(cnt, 0, (size_t)N_NODES * 4, stream);
  k_hist<<<(E_TOT + 255) / 256, 256, 0, stream>>>(ei, cnt);
  k_scan<<<1, 1024, 0, stream>>>(cnt, rowptr, cursor);
  k_scatter<<<(E_TOT + 255) / 256, 256, 0, stream>>>(ei, cursor, csr);

  // ---- layer 1: 128 -> 4x64, concat, ELU
  {
    dim3 g((N_NODES + 63) / 64, 256 / 64);
    k_gemm<<<g, 256, 0, stream>>>(x, W1, hA, N_NODES, 256, 128);
  }
  k_att<4><<<(N_NODES + 3) / 4, 256, 0, stream>>>(hA, as1, ad1, aS, aD);
  k_aggr<4, true><<<(N_NODES * 4 + 3) / 4, 256, 0, stream>>>(rowptr, csr, hA, aS, aD, b1, hB);

  // ---- layer 2: 256 -> 2x64, concat, ELU
  {
    dim3 g((N_NODES + 63) / 64, 128 / 64);
    k_gemm<<<g, 256, 0, stream>>>(hB, W2, hA, N_NODES, 128, 256);
  }
  k_att<2><<<(N_NODES + 3) / 4, 256, 0, stream>>>(hA, as2, ad2, aS, aD);
  k_aggr<2, true><<<(N_NODES * 2 + 3) / 4, 256, 0, stream>>>(rowptr, csr, hA, aS, aD, b2, hB);

  // ---- layer 3: 128 -> 2, mean(1 head), bias, log_softmax
  k_proj3<<<(N_NODES + 255) / 256, 256, 0, stream>>>(hB, W3, as3, ad3, h3, a3s, a3d);
  k_aggr3<<<(N_NODES + 255) / 256, 256, 0, stream>>>(rowptr, csr, h3, a3s, a3d, b3, out);
}

// Round 2
// 478.041 us; speedup vs baseline: 1.7886x; 1.7886x over previous
//
#include <hip/hip_runtime.h>

#define N_NODES 50000
#define N_EDGES 800000
#define E_TOT   (N_EDGES + N_NODES)   // 850000, self-loops appended at end

// ---------------------------------------------------------------- bf16 helpers
__device__ __forceinline__ float bflo(unsigned int p) {
  union { unsigned int u; float f; } v; v.u = p << 16; return v.f;
}
__device__ __forceinline__ float bfhi(unsigned int p) {
  union { unsigned int u; float f; } v; v.u = p & 0xFFFF0000u; return v.f;
}
__device__ __forceinline__ unsigned short f2bf(float f) {
  union { float f; unsigned int u; } v; v.f = f;
  unsigned int r = v.u + 0x7FFFu + ((v.u >> 16) & 1u);
  return (unsigned short)(r >> 16);
}

// ---------------------------------------------------------------- CSR build
__global__ void k_hist(const int* __restrict__ ei, int* __restrict__ cnt) {
  int e = blockIdx.x * blockDim.x + threadIdx.x;
  if (e >= E_TOT) return;
  int d = (e < N_EDGES) ? ei[N_EDGES + e] : (e - N_EDGES);
  atomicAdd(&cnt[d], 1);
}

__global__ __launch_bounds__(1024) void k_scan(const int* __restrict__ cnt,
                                               int* __restrict__ rowptr,
                                               int* __restrict__ cursor) {
  __shared__ int sums[1024];
  const int STRIP = (N_NODES + 1023) / 1024;  // 49
  int t = threadIdx.x;
  int lo = t * STRIP;
  int hi = lo + STRIP; if (hi > N_NODES) hi = N_NODES;
  if (lo > N_NODES) lo = N_NODES;
  int s = 0;
  for (int i = lo; i < hi; ++i) s += cnt[i];
  sums[t] = s;
  __syncthreads();
  for (int off = 1; off < 1024; off <<= 1) {
    int v = (t >= off) ? sums[t - off] : 0;
    __syncthreads();
    sums[t] += v;
    __syncthreads();
  }
  int run = sums[t] - s;  // exclusive prefix of strip sums
  for (int i = lo; i < hi; ++i) {
    rowptr[i] = run; cursor[i] = run;
    run += cnt[i];
  }
  if (t == 1023) rowptr[N_NODES] = sums[1023];
}

__global__ void k_scatter(const int* __restrict__ ei, int* __restrict__ cursor,
                          int* __restrict__ csr) {
  int e = blockIdx.x * blockDim.x + threadIdx.x;
  if (e >= E_TOT) return;
  int s, d;
  if (e < N_EDGES) { s = ei[e]; d = ei[N_EDGES + e]; }
  else             { s = d = e - N_EDGES; }
  int pos = atomicAdd(&cursor[d], 1);
  csr[pos] = s;
}

// ------------------------------------------------ fp32 GEMM + fused epilogue
// C[M,NN] = A[M,KD] @ B[KD,NN]; 64x64 tile. blockIdx.y == head (64-col tile
// aligns exactly with one head), so the per-row attention dot completes
// inside this block: write aS/aD fp32 and the h tile as bf16.
template <int NN, int KD, int H>
__global__ __launch_bounds__(256) void k_gemm_fused(
    const float* __restrict__ A, const float* __restrict__ B,
    const float* __restrict__ atts, const float* __restrict__ attd,
    unsigned short* __restrict__ hq, float* __restrict__ aS,
    float* __restrict__ aD, int M) {
  __shared__ float As[16][64];
  __shared__ float Bs[16][64];
  int row0 = blockIdx.x * 64;
  int hh   = blockIdx.y;
  int n0   = hh * 64;
  int t = threadIdx.x;
  int tx = t & 15, ty = t >> 4;
  int r0 = ty * 4, c0 = tx * 4;
  float acc[4][4] = {};
  for (int kc = 0; kc < KD; kc += 16) {
    {  // A tile
      int r = t >> 2, kq = (t & 3) * 4;
      int gr = row0 + r;
      float4 a4 = make_float4(0.f, 0.f, 0.f, 0.f);
      if (gr < M) a4 = *(const float4*)&A[(size_t)gr * KD + kc + kq];
      As[kq + 0][r] = a4.x; As[kq + 1][r] = a4.y;
      As[kq + 2][r] = a4.z; As[kq + 3][r] = a4.w;
    }
    {  // B tile
      int c = t & 63, kr = t >> 6;
      #pragma unroll
      for (int p = 0; p < 4; ++p)
        Bs[kr + p * 4][c] = B[(size_t)(kc + kr + p * 4) * NN + n0 + c];
    }
    __syncthreads();
    #pragma unroll
    for (int kk = 0; kk < 16; ++kk) {
      float4 a4 = *(const float4*)&As[kk][r0];
      float4 b4 = *(const float4*)&Bs[kk][c0];
      float av[4] = {a4.x, a4.y, a4.z, a4.w};
      float bv[4] = {b4.x, b4.y, b4.z, b4.w};
      #pragma unroll
      for (int i = 0; i < 4; ++i)
        #pragma unroll
        for (int j = 0; j < 4; ++j)
          acc[i][j] += av[i] * bv[j];
    }
    __syncthreads();
  }
  // attention partial dots over this thread's 4 columns
  float w_s[4], w_d[4];
  #pragma unroll
  for (int j = 0; j < 4; ++j) { w_s[j] = atts[n0 + c0 + j]; w_d[j] = attd[n0 + c0 + j]; }
  float ps[4] = {}, pd[4] = {};
  #pragma unroll
  for (int i = 0; i < 4; ++i)
    #pragma unroll
    for (int j = 0; j < 4; ++j) {
      ps[i] += acc[i][j] * w_s[j];
      pd[i] += acc[i][j] * w_d[j];
    }
  // reduce across the 16 lanes (tx) covering the 64 cols of each row
  #pragma unroll
  for (int off = 1; off < 16; off <<= 1)
    #pragma unroll
    for (int i = 0; i < 4; ++i) {
      ps[i] += __shfl_xor(ps[i], off);
      pd[i] += __shfl_xor(pd[i], off);
    }
  #pragma unroll
  for (int i = 0; i < 4; ++i) {
    int gr = row0 + r0 + i;
    if (gr < M) {
      ushort4 u = make_ushort4(f2bf(acc[i][0]), f2bf(acc[i][1]),
                               f2bf(acc[i][2]), f2bf(acc[i][3]));
      *(ushort4*)&hq[(size_t)gr * NN + n0 + c0] = u;
      if (tx == 0) {
        aS[(size_t)gr * H + hh] = ps[i];
        aD[(size_t)gr * H + hh] = pd[i];
      }
    }
  }
}

// ---------------------------------------------- raw-load typing for H=4 / H=2
template <int H> struct Raw;
template <> struct Raw<4> { using T = uint2; };
template <> struct Raw<2> { using T = unsigned int; };

template <int H>
__device__ __forceinline__ void unpack(typename Raw<H>::T q, float* v);
template <>
__device__ __forceinline__ void unpack<4>(uint2 q, float* v) {
  v[0] = bflo(q.x); v[1] = bfhi(q.x); v[2] = bflo(q.y); v[3] = bfhi(q.y);
}
template <>
__device__ __forceinline__ void unpack<2>(unsigned int q, float* v) {
  v[0] = bflo(q); v[1] = bfhi(q);
}

// -------------------------- edge-softmax + aggregate: one wave per node,
// all H heads at once; branchless per-lane online softmax; bf16 gather.
template <int H, bool ELU>
__global__ void k_aggr(const int* __restrict__ rowptr, const int* __restrict__ csr,
                       const unsigned short* __restrict__ hq,
                       const float* __restrict__ aS, const float* __restrict__ aD,
                       const float* __restrict__ bias, float* __restrict__ out) {
  int n    = (int)((blockIdx.x * (size_t)blockDim.x + threadIdx.x) >> 6);
  int lane = threadIdx.x & 63;
  if (n >= N_NODES) return;
  constexpr int C = H * 64;
  int hl = (lane * H) >> 6;  // head owning this lane's H channels
  float adv = aD[(size_t)n * H + hl];
  float m = -1e30f, s = 0.f;
  float acc[H] = {};
  int lo = rowptr[n], hi = rowptr[n + 1];
  // 1-deep software pipeline over edges
  int j = csr[lo];
  float a = aS[(size_t)j * H + hl];
  typename Raw<H>::T u = *(const typename Raw<H>::T*)&hq[(size_t)j * C + lane * H];
  for (int k = lo; k < hi; ++k) {
    int kn = (k + 1 < hi) ? k + 1 : k;
    int jn = csr[kn];
    float an = aS[(size_t)jn * H + hl];
    typename Raw<H>::T un = *(const typename Raw<H>::T*)&hq[(size_t)jn * C + lane * H];
    float hv[H];
    unpack<H>(u, hv);
    float e = a + adv;
    e = e > 0.f ? e : 0.2f * e;
    float nm = fmaxf(m, e);
    float sc = __expf(m - nm);
    float w  = __expf(e - nm);
    s = s * sc + w;
    #pragma unroll
    for (int c = 0; c < H; ++c) acc[c] = acc[c] * sc + w * hv[c];
    m = nm;
    a = an; u = un;
  }
  float inv = 1.f / s;
  float o[H];
  #pragma unroll
  for (int c = 0; c < H; ++c) {
    float v = acc[c] * inv + bias[lane * H + c];
    if (ELU) v = v > 0.f ? v : __expf(v) - 1.f;
    o[c] = v;
  }
  size_t idx = (size_t)n * C + lane * H;
  if constexpr (H == 4)
    *(float4*)&out[idx] = make_float4(o[0], o[1], o[2], o[3]);
  else
    *(float2*)&out[idx] = make_float2(o[0], o[1]);
}

// --------------------------------------------------------- layer-3 (C=2, H=1)
__global__ void k_proj3(const float* __restrict__ hin, const float* __restrict__ W3,
                        const float* __restrict__ s3, const float* __restrict__ d3,
                        float* __restrict__ h3, float* __restrict__ a3s,
                        float* __restrict__ a3d) {
  int n = blockIdx.x * blockDim.x + threadIdx.x;
  if (n >= N_NODES) return;
  float a0 = 0.f, a1 = 0.f;
  const float4* hp = (const float4*)(hin + (size_t)n * 128);
  #pragma unroll
  for (int q = 0; q < 32; ++q) {
    float4 v = hp[q];
    const float* w = W3 + q * 8;
    a0 += v.x * w[0] + v.y * w[2] + v.z * w[4] + v.w * w[6];
    a1 += v.x * w[1] + v.y * w[3] + v.z * w[5] + v.w * w[7];
  }
  h3[(size_t)n * 2]     = a0;
  h3[(size_t)n * 2 + 1] = a1;
  a3s[n] = a0 * s3[0] + a1 * s3[1];
  a3d[n] = a0 * d3[0] + a1 * d3[1];
}

__global__ void k_aggr3(const int* __restrict__ rowptr, const int* __restrict__ csr,
                        const float* __restrict__ h3, const float* __restrict__ a3s,
                        const float* __restrict__ a3d, const float* __restrict__ b3,
                        float* __restrict__ out) {
  int n = blockIdx.x * blockDim.x + threadIdx.x;
  if (n >= N_NODES) return;
  float adv = a3d[n];
  float m = -1e30f, s = 0.f, acc0 = 0.f, acc1 = 0.f;
  int lo = rowptr[n], hi = rowptr[n + 1];
  for (int k = lo; k < hi; ++k) {
    int j = csr[k];
    float e = a3s[j] + adv;
    e = e > 0.f ? e : 0.2f * e;
    float h0 = h3[(size_t)j * 2], h1 = h3[(size_t)j * 2 + 1];
    float nm = fmaxf(m, e);
    float sc = __expf(m - nm);
    float w  = __expf(e - nm);
    s = s * sc + w; acc0 = acc0 * sc + w * h0; acc1 = acc1 * sc + w * h1;
    m = nm;
  }
  float o0 = acc0 / s + b3[0];
  float o1 = acc1 / s + b3[1];
  float mx = fmaxf(o0, o1);
  float l  = logf(__expf(o0 - mx) + __expf(o1 - mx));
  out[(size_t)n * 2]     = o0 - mx - l;
  out[(size_t)n * 2 + 1] = o1 - mx - l;
}

// ---------------------------------------------------------------- launcher
extern "C" void kernel_launch(void* const* d_in, const int* in_sizes, int n_in,
                              void* d_out, int out_size, void* d_ws, size_t ws_size,
                              hipStream_t stream) {
  const float* x   = (const float*)d_in[0];
  const int*   ei  = (const int*)d_in[1];
  const float* W1  = (const float*)d_in[2];
  const float* as1 = (const float*)d_in[3];
  const float* ad1 = (const float*)d_in[4];
  const float* b1  = (const float*)d_in[5];
  const float* W2  = (const float*)d_in[6];
  const float* as2 = (const float*)d_in[7];
  const float* ad2 = (const float*)d_in[8];
  const float* b2  = (const float*)d_in[9];
  const float* W3  = (const float*)d_in[10];
  const float* as3 = (const float*)d_in[11];
  const float* ad3 = (const float*)d_in[12];
  const float* b3  = (const float*)d_in[13];
  float* out = (float*)d_out;

  char* p = (char*)d_ws;
  auto alloc = [&](size_t bytes) -> char* {
    char* r = p; p += (bytes + 255) & ~(size_t)255; return r;
  };
  int*   cnt    = (int*)alloc((size_t)N_NODES * 4);
  int*   rowptr = (int*)alloc((size_t)(N_NODES + 1) * 4);
  int*   cursor = (int*)alloc((size_t)N_NODES * 4);
  int*   csr    = (int*)alloc((size_t)E_TOT * 4);
  float* aS     = (float*)alloc((size_t)N_NODES * 4 * 4);
  float* aD     = (float*)alloc((size_t)N_NODES * 4 * 4);
  float* h3     = (float*)alloc((size_t)N_NODES * 2 * 4);
  float* a3s    = (float*)alloc((size_t)N_NODES * 4);
  float* a3d    = (float*)alloc((size_t)N_NODES * 4);
  unsigned short* hq1 = (unsigned short*)alloc((size_t)N_NODES * 256 * 2);  // bf16 h1
  float* hB     = (float*)alloc((size_t)N_NODES * 256 * 4);                 // fp32 L1 out
  unsigned short* hq2 = (unsigned short*)alloc((size_t)N_NODES * 128 * 2);  // bf16 h2
  float* h2o    = (float*)hq1;  // L2 out (25.6 MB) aliases dead hq1

  // CSR (reused by all three layers)
  hipMemsetAsync(cnt, 0, (size_t)N_NODES * 4, stream);
  k_hist<<<(E_TOT + 255) / 256, 256, 0, stream>>>(ei, cnt);
  k_scan<<<1, 1024, 0, stream>>>(cnt, rowptr, cursor);
  k_scatter<<<(E_TOT + 255) / 256, 256, 0, stream>>>(ei, cursor, csr);

  const int GB = (N_NODES + 63) / 64;  // 782

  // ---- layer 1: 128 -> 4x64, concat, ELU
  k_gemm_fused<256, 128, 4><<<dim3(GB, 4), 256, 0, stream>>>(
      x, W1, as1, ad1, hq1, aS, aD, N_NODES);
  k_aggr<4, true><<<(N_NODES + 3) / 4, 256, 0, stream>>>(
      rowptr, csr, hq1, aS, aD, b1, hB);

  // ---- layer 2: 256 -> 2x64, concat, ELU
  k_gemm_fused<128, 256, 2><<<dim3(GB, 2), 256, 0, stream>>>(
      hB, W2, as2, ad2, hq2, aS, aD, N_NODES);
  k_aggr<2, true><<<(N_NODES + 3) / 4, 256, 0, stream>>>(
      rowptr, csr, hq2, aS, aD, b2, h2o);

  // ---- layer 3: 128 -> 2, mean(1 head), bias, log_softmax
  k_proj3<<<(N_NODES + 255) / 256, 256, 0, stream>>>(h2o, W3, as3, ad3, h3, a3s, a3d);
  k_aggr3<<<(N_NODES + 255) / 256, 256, 0, stream>>>(rowptr, csr, h3, a3s, a3d, b3, out);
}

// Round 3
// 306.756 us; speedup vs baseline: 2.7874x; 1.5584x over previous
//
#include <hip/hip_runtime.h>

#define N_NODES 50000
#define N_EDGES 800000
#define E_TOT   (N_EDGES + N_NODES)   // 850000, self-loops appended at end
#define SCAN_B  ((N_NODES + 255) / 256)  // 196

using bfrag = __attribute__((ext_vector_type(8))) short;
using f32x4 = __attribute__((ext_vector_type(4))) float;

// ---------------------------------------------------------------- bf16 helpers
__device__ __forceinline__ float bflo(unsigned int p) {
  union { unsigned int u; float f; } v; v.u = p << 16; return v.f;
}
__device__ __forceinline__ float bfhi(unsigned int p) {
  union { unsigned int u; float f; } v; v.u = p & 0xFFFF0000u; return v.f;
}
__device__ __forceinline__ unsigned short f2bf(float f) {
  union { float f; unsigned int u; } v; v.f = f;
  unsigned int r = v.u + 0x7FFFu + ((v.u >> 16) & 1u);
  return (unsigned short)(r >> 16);
}

// ---------------------------------------------------------------- conversions
__global__ void k_f2bf(const float* __restrict__ in, unsigned short* __restrict__ out,
                       int n4) {
  int i = blockIdx.x * blockDim.x + threadIdx.x;
  if (i >= n4) return;
  float4 v = *(const float4*)&in[(size_t)i * 4];
  *(ushort4*)&out[(size_t)i * 4] =
      make_ushort4(f2bf(v.x), f2bf(v.y), f2bf(v.z), f2bf(v.w));
}

// W[K][N] fp32 -> Wt[N][K] bf16
template <int K, int N>
__global__ void k_wt(const float* __restrict__ W, unsigned short* __restrict__ Wt) {
  int i = blockIdx.x * blockDim.x + threadIdx.x;
  if (i >= K * N) return;
  int k = i / N, n = i - k * N;
  Wt[n * K + k] = f2bf(W[i]);
}

// ---------------------------------------------------------------- CSR build
__global__ void k_hist(const int* __restrict__ ei, int* __restrict__ cnt) {
  int e = blockIdx.x * blockDim.x + threadIdx.x;
  if (e >= E_TOT) return;
  int d = (e < N_EDGES) ? ei[N_EDGES + e] : (e - N_EDGES);
  atomicAdd(&cnt[d], 1);
}

__global__ void k_bsum(const int* __restrict__ cnt, int* __restrict__ bsum) {
  int t = threadIdx.x;
  int i = blockIdx.x * 256 + t;
  int v = (i < N_NODES) ? cnt[i] : 0;
  #pragma unroll
  for (int off = 32; off; off >>= 1) v += __shfl_down(v, off);
  __shared__ int ws[4];
  if ((t & 63) == 0) ws[t >> 6] = v;
  __syncthreads();
  if (t == 0) bsum[blockIdx.x] = ws[0] + ws[1] + ws[2] + ws[3];
}

__global__ void k_bscan(const int* __restrict__ bsum, int* __restrict__ boff) {
  __shared__ int s[256];
  int t = threadIdx.x;
  int v = (t < SCAN_B) ? bsum[t] : 0;
  s[t] = v;
  __syncthreads();
  for (int off = 1; off < 256; off <<= 1) {
    int x = (t >= off) ? s[t - off] : 0;
    __syncthreads();
    s[t] += x;
    __syncthreads();
  }
  boff[t] = s[t] - v;  // exclusive
}

__global__ void k_rowptr(const int* __restrict__ cnt, const int* __restrict__ boff,
                         int* __restrict__ rowptr, int* __restrict__ cursor) {
  __shared__ int s[256];
  int t = threadIdx.x;
  int i = blockIdx.x * 256 + t;
  int v = (i < N_NODES) ? cnt[i] : 0;
  s[t] = v;
  __syncthreads();
  for (int off = 1; off < 256; off <<= 1) {
    int x = (t >= off) ? s[t - off] : 0;
    __syncthreads();
    s[t] += x;
    __syncthreads();
  }
  int excl = boff[blockIdx.x] + s[t] - v;
  if (i < N_NODES) { rowptr[i] = excl; cursor[i] = excl; }
  if (i == N_NODES - 1) rowptr[N_NODES] = excl + v;
}

__global__ void k_scatter(const int* __restrict__ ei, int* __restrict__ cursor,
                          int* __restrict__ csr) {
  int e = blockIdx.x * blockDim.x + threadIdx.x;
  if (e >= E_TOT) return;
  int s, d;
  if (e < N_EDGES) { s = ei[e]; d = ei[N_EDGES + e]; }
  else             { s = d = e - N_EDGES; }
  int pos = atomicAdd(&cursor[d], 1);
  csr[pos] = s;
}

// ------------------------------------------- MFMA bf16 GEMM + fused epilogue
// C[M,NN] = A[M,KD] @ B[KD,NN], NN = H*64, blockIdx.y = head (64 cols).
// Block: 256 threads = 4 waves, each wave 16 rows x 64 cols.
// B staged in LDS from Wt[N][K] with XOR-swizzled 16B granules.
// Epilogue: aS/aD attention dots (fp32, from accum) + bf16 h write.
template <int KD, int H>
__global__ __launch_bounds__(256) void k_gemm_mfma(
    const unsigned short* __restrict__ Aq, const unsigned short* __restrict__ Wt,
    const float* __restrict__ atts, const float* __restrict__ attd,
    unsigned short* __restrict__ hq, float* __restrict__ aS,
    float* __restrict__ aD, int M) {
  constexpr int NN = H * 64;
  __shared__ unsigned short Bts[64 * KD];
  int hh = blockIdx.y;
  int n0 = hh * 64;
  int t = threadIdx.x;
  // ---- stage B tile (cols n0..n0+63, all K) with swizzle
  #pragma unroll
  for (int c = 0; c < KD / 32; ++c) {
    int chunk = t + c * 256;            // 16B granule id
    int col = chunk / (KD / 8);
    int kc  = chunk % (KD / 8);
    uint4 v = *(const uint4*)&Wt[(size_t)(n0 + col) * KD + kc * 8];
    int swz = kc ^ (col & 7);
    *(uint4*)&Bts[col * KD + swz * 8] = v;
  }
  __syncthreads();

  int lane = t & 63;
  int w = t >> 6;
  int arow = blockIdx.x * 64 + w * 16 + (lane & 15);
  int arow_c = arow < M ? arow : M - 1;  // clamp: junk rows only affect discarded D rows
  const unsigned short* Arow = Aq + (size_t)arow_c * KD;

  f32x4 acc[4] = {};
  for (int k0 = 0; k0 < KD; k0 += 32) {
    int g = (k0 >> 3) + (lane >> 4);    // 16B granule along K for this lane
    bfrag a = *(const bfrag*)&Arow[g * 8];
    #pragma unroll
    for (int cf = 0; cf < 4; ++cf) {
      int col = cf * 16 + (lane & 15);
      int gs = g ^ (col & 7);
      bfrag b = *(const bfrag*)&Bts[col * KD + gs * 8];
      acc[cf] = __builtin_amdgcn_mfma_f32_16x16x32_bf16(a, b, acc[cf], 0, 0, 0);
    }
  }

  // ---- fused epilogue
  float ws_[4], wd_[4];
  #pragma unroll
  for (int cf = 0; cf < 4; ++cf) {
    ws_[cf] = atts[n0 + cf * 16 + (lane & 15)];
    wd_[cf] = attd[n0 + cf * 16 + (lane & 15)];
  }
  float ps[4] = {}, pd[4] = {};
  #pragma unroll
  for (int cf = 0; cf < 4; ++cf)
    #pragma unroll
    for (int i = 0; i < 4; ++i) {
      ps[i] += acc[cf][i] * ws_[cf];
      pd[i] += acc[cf][i] * wd_[cf];
    }
  #pragma unroll
  for (int off = 1; off < 16; off <<= 1)
    #pragma unroll
    for (int i = 0; i < 4; ++i) {
      ps[i] += __shfl_xor(ps[i], off);
      pd[i] += __shfl_xor(pd[i], off);
    }
  int orow0 = blockIdx.x * 64 + w * 16 + (lane >> 4) * 4;
  #pragma unroll
  for (int i = 0; i < 4; ++i) {
    int r = orow0 + i;
    if (r < M) {
      #pragma unroll
      for (int cf = 0; cf < 4; ++cf)
        hq[(size_t)r * NN + n0 + cf * 16 + (lane & 15)] = f2bf(acc[cf][i]);
      if ((lane & 15) == 0) {
        aS[(size_t)r * H + hh] = ps[i];
        aD[(size_t)r * H + hh] = pd[i];
      }
    }
  }
}

// ---------------------------------------------- raw-load typing for H=4 / H=2
template <int H> struct Raw;
template <> struct Raw<4> { using T = uint2; };
template <> struct Raw<2> { using T = unsigned int; };

template <int H>
__device__ __forceinline__ void unpack(typename Raw<H>::T q, float* v);
template <>
__device__ __forceinline__ void unpack<4>(uint2 q, float* v) {
  v[0] = bflo(q.x); v[1] = bfhi(q.x); v[2] = bflo(q.y); v[3] = bfhi(q.y);
}
template <>
__device__ __forceinline__ void unpack<2>(unsigned int q, float* v) {
  v[0] = bflo(q); v[1] = bfhi(q);
}

// ---------------- edge-softmax + aggregate: one wave per node, all H heads;
// dual interleaved online-softmax states (even/odd edges) for 2x MLP.
template <int H, bool ELU, bool OBF>
__global__ void k_aggr(const int* __restrict__ rowptr, const int* __restrict__ csr,
                       const unsigned short* __restrict__ hq,
                       const float* __restrict__ aS, const float* __restrict__ aD,
                       const float* __restrict__ bias, void* __restrict__ outv) {
  int n    = (int)((blockIdx.x * (size_t)blockDim.x + threadIdx.x) >> 6);
  int lane = threadIdx.x & 63;
  if (n >= N_NODES) return;
  constexpr int C = H * 64;
  int hl = (lane * H) >> 6;
  float adv = aD[(size_t)n * H + hl];
  int lo = rowptr[n], hi = rowptr[n + 1];
  float m0 = -1e30f, s0 = 0.f, m1 = -1e30f, s1 = 0.f;
  float A0[H] = {}, A1[H] = {};
  int k = lo;
  for (; k + 1 < hi; k += 2) {
    int ja = csr[k], jb = csr[k + 1];
    float ea = aS[(size_t)ja * H + hl];
    float eb = aS[(size_t)jb * H + hl];
    typename Raw<H>::T ua = *(const typename Raw<H>::T*)&hq[(size_t)ja * C + lane * H];
    typename Raw<H>::T ub = *(const typename Raw<H>::T*)&hq[(size_t)jb * C + lane * H];
    float ha[H], hb[H];
    unpack<H>(ua, ha);
    unpack<H>(ub, hb);
    ea += adv; ea = ea > 0.f ? ea : 0.2f * ea;
    eb += adv; eb = eb > 0.f ? eb : 0.2f * eb;
    float nm0 = fmaxf(m0, ea), sc0 = __expf(m0 - nm0), w0 = __expf(ea - nm0);
    s0 = s0 * sc0 + w0;
    #pragma unroll
    for (int c = 0; c < H; ++c) A0[c] = A0[c] * sc0 + w0 * ha[c];
    m0 = nm0;
    float nm1 = fmaxf(m1, eb), sc1 = __expf(m1 - nm1), w1 = __expf(eb - nm1);
    s1 = s1 * sc1 + w1;
    #pragma unroll
    for (int c = 0; c < H; ++c) A1[c] = A1[c] * sc1 + w1 * hb[c];
    m1 = nm1;
  }
  if (k < hi) {
    int ja = csr[k];
    float ea = aS[(size_t)ja * H + hl] + adv;
    ea = ea > 0.f ? ea : 0.2f * ea;
    typename Raw<H>::T ua = *(const typename Raw<H>::T*)&hq[(size_t)ja * C + lane * H];
    float ha[H];
    unpack<H>(ua, ha);
    float nm0 = fmaxf(m0, ea), sc0 = __expf(m0 - nm0), w0 = __expf(ea - nm0);
    s0 = s0 * sc0 + w0;
    #pragma unroll
    for (int c = 0; c < H; ++c) A0[c] = A0[c] * sc0 + w0 * ha[c];
    m0 = nm0;
  }
  // merge the two states (empty state1: exp(-1e30-m) == 0)
  float m = fmaxf(m0, m1);
  float e0 = __expf(m0 - m), e1 = __expf(m1 - m);
  float inv = 1.f / (s0 * e0 + s1 * e1);
  float o[H];
  #pragma unroll
  for (int c = 0; c < H; ++c) {
    float v = (A0[c] * e0 + A1[c] * e1) * inv + bias[lane * H + c];
    if (ELU) v = v > 0.f ? v : __expf(v) - 1.f;
    o[c] = v;
  }
  size_t idx = (size_t)n * C + lane * H;
  if constexpr (OBF) {
    unsigned short* outp = (unsigned short*)outv;
    if constexpr (H == 4)
      *(ushort4*)&outp[idx] = make_ushort4(f2bf(o[0]), f2bf(o[1]), f2bf(o[2]), f2bf(o[3]));
    else
      *(unsigned int*)&outp[idx] = (unsigned int)f2bf(o[0]) | ((unsigned int)f2bf(o[1]) << 16);
  } else {
    float* outp = (float*)outv;
    if constexpr (H == 4)
      *(float4*)&outp[idx] = make_float4(o[0], o[1], o[2], o[3]);
    else
      *(float2*)&outp[idx] = make_float2(o[0], o[1]);
  }
}

// --------------------------------------------------------- layer-3 (C=2, H=1)
__global__ void k_proj3(const float* __restrict__ hin, const float* __restrict__ W3,
                        const float* __restrict__ s3, const float* __restrict__ d3,
                        float* __restrict__ h3, float* __restrict__ a3s,
                        float* __restrict__ a3d) {
  int n = blockIdx.x * blockDim.x + threadIdx.x;
  if (n >= N_NODES) return;
  float a0 = 0.f, a1 = 0.f;
  const float4* hp = (const float4*)(hin + (size_t)n * 128);
  #pragma unroll
  for (int q = 0; q < 32; ++q) {
    float4 v = hp[q];
    const float* w = W3 + q * 8;
    a0 += v.x * w[0] + v.y * w[2] + v.z * w[4] + v.w * w[6];
    a1 += v.x * w[1] + v.y * w[3] + v.z * w[5] + v.w * w[7];
  }
  h3[(size_t)n * 2]     = a0;
  h3[(size_t)n * 2 + 1] = a1;
  a3s[n] = a0 * s3[0] + a1 * s3[1];
  a3d[n] = a0 * d3[0] + a1 * d3[1];
}

__global__ void k_aggr3(const int* __restrict__ rowptr, const int* __restrict__ csr,
                        const float* __restrict__ h3, const float* __restrict__ a3s,
                        const float* __restrict__ a3d, const float* __restrict__ b3,
                        float* __restrict__ out) {
  int n = blockIdx.x * blockDim.x + threadIdx.x;
  if (n >= N_NODES) return;
  float adv = a3d[n];
  float m = -1e30f, s = 0.f, acc0 = 0.f, acc1 = 0.f;
  int lo = rowptr[n], hi = rowptr[n + 1];
  for (int k = lo; k < hi; ++k) {
    int j = csr[k];
    float e = a3s[j] + adv;
    e = e > 0.f ? e : 0.2f * e;
    float h0 = h3[(size_t)j * 2], h1 = h3[(size_t)j * 2 + 1];
    float nm = fmaxf(m, e);
    float sc = __expf(m - nm);
    float w  = __expf(e - nm);
    s = s * sc + w; acc0 = acc0 * sc + w * h0; acc1 = acc1 * sc + w * h1;
    m = nm;
  }
  float o0 = acc0 / s + b3[0];
  float o1 = acc1 / s + b3[1];
  float mx = fmaxf(o0, o1);
  float l  = logf(__expf(o0 - mx) + __expf(o1 - mx));
  out[(size_t)n * 2]     = o0 - mx - l;
  out[(size_t)n * 2 + 1] = o1 - mx - l;
}

// ---------------------------------------------------------------- launcher
extern "C" void kernel_launch(void* const* d_in, const int* in_sizes, int n_in,
                              void* d_out, int out_size, void* d_ws, size_t ws_size,
                              hipStream_t stream) {
  const float* x   = (const float*)d_in[0];
  const int*   ei  = (const int*)d_in[1];
  const float* W1  = (const float*)d_in[2];
  const float* as1 = (const float*)d_in[3];
  const float* ad1 = (const float*)d_in[4];
  const float* b1  = (const float*)d_in[5];
  const float* W2  = (const float*)d_in[6];
  const float* as2 = (const float*)d_in[7];
  const float* ad2 = (const float*)d_in[8];
  const float* b2  = (const float*)d_in[9];
  const float* W3  = (const float*)d_in[10];
  const float* as3 = (const float*)d_in[11];
  const float* ad3 = (const float*)d_in[12];
  const float* b3  = (const float*)d_in[13];
  float* out = (float*)d_out;

  char* p = (char*)d_ws;
  auto alloc = [&](size_t bytes) -> char* {
    char* r = p; p += (bytes + 255) & ~(size_t)255; return r;
  };
  int*   cnt    = (int*)alloc((size_t)N_NODES * 4);
  int*   rowptr = (int*)alloc((size_t)(N_NODES + 1) * 4);
  int*   cursor = (int*)alloc((size_t)N_NODES * 4);
  int*   csr    = (int*)alloc((size_t)E_TOT * 4);
  int*   bsum   = (int*)alloc(256 * 4);
  int*   boff   = (int*)alloc(257 * 4);
  float* aS     = (float*)alloc((size_t)N_NODES * 4 * 4);
  float* aD     = (float*)alloc((size_t)N_NODES * 4 * 4);
  float* h3     = (float*)alloc((size_t)N_NODES * 2 * 4);
  float* a3s    = (float*)alloc((size_t)N_NODES * 4);
  float* a3d    = (float*)alloc((size_t)N_NODES * 4);
  unsigned short* xq  = (unsigned short*)alloc((size_t)N_NODES * 128 * 2);
  unsigned short* W1t = (unsigned short*)alloc((size_t)256 * 128 * 2);
  unsigned short* W2t = (unsigned short*)alloc((size_t)128 * 256 * 2);
  unsigned short* hq1 = (unsigned short*)alloc((size_t)N_NODES * 256 * 2);  // gemm1 out
  unsigned short* hBq = (unsigned short*)alloc((size_t)N_NODES * 256 * 2);  // aggr1 out
  unsigned short* hq2 = (unsigned short*)alloc((size_t)N_NODES * 128 * 2);  // gemm2 out
  float* h2o = (float*)hq1;  // aggr2 out (25.6 MB) aliases dead hq1

  // ---- input conversions (bf16)
  k_f2bf<<<(N_NODES * 128 / 4 + 255) / 256, 256, 0, stream>>>(x, xq, N_NODES * 128 / 4);
  k_wt<128, 256><<<(128 * 256 + 255) / 256, 256, 0, stream>>>(W1, W1t);
  k_wt<256, 128><<<(256 * 128 + 255) / 256, 256, 0, stream>>>(W2, W2t);

  // ---- CSR (reused by all three layers)
  hipMemsetAsync(cnt, 0, (size_t)N_NODES * 4, stream);
  k_hist<<<(E_TOT + 255) / 256, 256, 0, stream>>>(ei, cnt);
  k_bsum<<<SCAN_B, 256, 0, stream>>>(cnt, bsum);
  k_bscan<<<1, 256, 0, stream>>>(bsum, boff);
  k_rowptr<<<SCAN_B, 256, 0, stream>>>(cnt, boff, rowptr, cursor);
  k_scatter<<<(E_TOT + 255) / 256, 256, 0, stream>>>(ei, cursor, csr);

  const int GB = (N_NODES + 63) / 64;  // 782

  // ---- layer 1: 128 -> 4x64, concat, ELU
  k_gemm_mfma<128, 4><<<dim3(GB, 4), 256, 0, stream>>>(
      xq, W1t, as1, ad1, hq1, aS, aD, N_NODES);
  k_aggr<4, true, true><<<(N_NODES + 3) / 4, 256, 0, stream>>>(
      rowptr, csr, hq1, aS, aD, b1, hBq);

  // ---- layer 2: 256 -> 2x64, concat, ELU
  k_gemm_mfma<256, 2><<<dim3(GB, 2), 256, 0, stream>>>(
      hBq, W2t, as2, ad2, hq2, aS, aD, N_NODES);
  k_aggr<2, true, false><<<(N_NODES + 3) / 4, 256, 0, stream>>>(
      rowptr, csr, hq2, aS, aD, b2, h2o);

  // ---- layer 3: 128 -> 2, mean(1 head), bias, log_softmax
  k_proj3<<<(N_NODES + 255) / 256, 256, 0, stream>>>(h2o, W3, as3, ad3, h3, a3s, a3d);
  k_aggr3<<<(N_NODES + 255) / 256, 256, 0, stream>>>(rowptr, csr, h3, a3s, a3d, b3, out);
}

// Round 4
// 291.824 us; speedup vs baseline: 2.9300x; 1.0512x over previous
//
#include <hip/hip_runtime.h>

#define N_NODES 50000
#define N_EDGES 800000
#define E_TOT   (N_EDGES + N_NODES)   // 850000, self-loops appended at end
#define SCAN_B  ((N_NODES + 255) / 256)  // 196

using bfrag = __attribute__((ext_vector_type(8))) short;
using f32x4 = __attribute__((ext_vector_type(4))) float;

// ---------------------------------------------------------------- bf16 helpers
__device__ __forceinline__ float bflo(unsigned int p) {
  union { unsigned int u; float f; } v; v.u = p << 16; return v.f;
}
__device__ __forceinline__ float bfhi(unsigned int p) {
  union { unsigned int u; float f; } v; v.u = p & 0xFFFF0000u; return v.f;
}
__device__ __forceinline__ unsigned short f2bf(float f) {
  union { float f; unsigned int u; } v; v.f = f;
  unsigned int r = v.u + 0x7FFFu + ((v.u >> 16) & 1u);
  return (unsigned short)(r >> 16);
}

// ---------------------------------------------------------------- conversions
__global__ void k_f2bf(const float* __restrict__ in, unsigned short* __restrict__ out,
                       int n4) {
  int i = blockIdx.x * blockDim.x + threadIdx.x;
  if (i >= n4) return;
  float4 v = *(const float4*)&in[(size_t)i * 4];
  *(ushort4*)&out[(size_t)i * 4] =
      make_ushort4(f2bf(v.x), f2bf(v.y), f2bf(v.z), f2bf(v.w));
}

// W[K][N] fp32 -> Wt[N][K] bf16
template <int K, int N>
__global__ void k_wt(const float* __restrict__ W, unsigned short* __restrict__ Wt) {
  int i = blockIdx.x * blockDim.x + threadIdx.x;
  if (i >= K * N) return;
  int k = i / N, n = i - k * N;
  Wt[n * K + k] = f2bf(W[i]);
}

// ---------------------------------------------------------------- CSR build
__global__ void k_hist(const int* __restrict__ ei, int* __restrict__ cnt) {
  int e = blockIdx.x * blockDim.x + threadIdx.x;
  if (e >= E_TOT) return;
  int d = (e < N_EDGES) ? ei[N_EDGES + e] : (e - N_EDGES);
  atomicAdd(&cnt[d], 1);
}

__global__ void k_bsum(const int* __restrict__ cnt, int* __restrict__ bsum) {
  int t = threadIdx.x;
  int i = blockIdx.x * 256 + t;
  int v = (i < N_NODES) ? cnt[i] : 0;
  #pragma unroll
  for (int off = 32; off; off >>= 1) v += __shfl_down(v, off);
  __shared__ int ws[4];
  if ((t & 63) == 0) ws[t >> 6] = v;
  __syncthreads();
  if (t == 0) bsum[blockIdx.x] = ws[0] + ws[1] + ws[2] + ws[3];
}

__global__ void k_bscan(const int* __restrict__ bsum, int* __restrict__ boff) {
  __shared__ int s[256];
  int t = threadIdx.x;
  int v = (t < SCAN_B) ? bsum[t] : 0;
  s[t] = v;
  __syncthreads();
  for (int off = 1; off < 256; off <<= 1) {
    int x = (t >= off) ? s[t - off] : 0;
    __syncthreads();
    s[t] += x;
    __syncthreads();
  }
  boff[t] = s[t] - v;  // exclusive
}

__global__ void k_rowptr(const int* __restrict__ cnt, const int* __restrict__ boff,
                         int* __restrict__ rowptr, int* __restrict__ cursor) {
  __shared__ int s[256];
  int t = threadIdx.x;
  int i = blockIdx.x * 256 + t;
  int v = (i < N_NODES) ? cnt[i] : 0;
  s[t] = v;
  __syncthreads();
  for (int off = 1; off < 256; off <<= 1) {
    int x = (t >= off) ? s[t - off] : 0;
    __syncthreads();
    s[t] += x;
    __syncthreads();
  }
  int excl = boff[blockIdx.x] + s[t] - v;
  if (i < N_NODES) { rowptr[i] = excl; cursor[i] = excl; }
  if (i == N_NODES - 1) rowptr[N_NODES] = excl + v;
}

__global__ void k_scatter(const int* __restrict__ ei, int* __restrict__ cursor,
                          int* __restrict__ csr) {
  int e = blockIdx.x * blockDim.x + threadIdx.x;
  if (e >= E_TOT) return;
  int s, d;
  if (e < N_EDGES) { s = ei[e]; d = ei[N_EDGES + e]; }
  else             { s = d = e - N_EDGES; }
  int pos = atomicAdd(&cursor[d], 1);
  csr[pos] = s;
}

// ------------------------------------------- MFMA bf16 GEMM + fused epilogue
// Full-width: one block computes ALL H heads (NN = H*64 cols) for 64 rows.
// B staged in LDS (32 KB) in two K-halves; A rows streamed from global once.
// Epilogue: per-head aS/aD attention dots (fp32) + bf16 h write.
template <int KD, int H>
__global__ __launch_bounds__(256) void k_gemm_mfma(
    const unsigned short* __restrict__ Aq, const unsigned short* __restrict__ Wt,
    const float* __restrict__ atts, const float* __restrict__ attd,
    unsigned short* __restrict__ hq, float* __restrict__ aS,
    float* __restrict__ aD, int M) {
  constexpr int NN = H * 64;
  constexpr int KH = KD / 2;              // K per half
  constexpr int GR = KH / 8;              // 16B granules per col per half
  __shared__ unsigned short Bts[NN * KH]; // 32 KB
  int t = threadIdx.x;
  int lane = t & 63;
  int w = t >> 6;
  int arow = blockIdx.x * 64 + w * 16 + (lane & 15);
  int arow_c = arow < M ? arow : M - 1;   // clamp: junk rows only hit discarded D rows
  const unsigned short* Arow = Aq + (size_t)arow_c * KD;

  f32x4 acc[NN / 16] = {};
  #pragma unroll
  for (int half = 0; half < 2; ++half) {
    if (half) __syncthreads();
    // ---- stage B half-tile (all NN cols, K range [half*KH, half*KH+KH))
    #pragma unroll
    for (int c = 0; c < NN * KH / 2048; ++c) {
      int chunk = t + c * 256;            // 16B granule id
      int col = chunk / GR;
      int kc  = chunk % GR;
      uint4 v = *(const uint4*)&Wt[(size_t)col * KD + half * KH + kc * 8];
      int swz = kc ^ (col & 7);
      *(uint4*)&Bts[col * KH + swz * 8] = v;
    }
    __syncthreads();
    for (int k0 = 0; k0 < KH; k0 += 32) {
      int gl = (k0 >> 3) + (lane >> 4);   // LDS granule
      bfrag a = *(const bfrag*)&Arow[half * KH + gl * 8];
      #pragma unroll
      for (int cf = 0; cf < NN / 16; ++cf) {
        int col = cf * 16 + (lane & 15);
        int gs = gl ^ (col & 7);
        bfrag b = *(const bfrag*)&Bts[col * KH + gs * 8];
        acc[cf] = __builtin_amdgcn_mfma_f32_16x16x32_bf16(a, b, acc[cf], 0, 0, 0);
      }
    }
  }

  // ---- fused epilogue
  float ws_[NN / 16], wd_[NN / 16];
  #pragma unroll
  for (int cf = 0; cf < NN / 16; ++cf) {
    ws_[cf] = atts[cf * 16 + (lane & 15)];
    wd_[cf] = attd[cf * 16 + (lane & 15)];
  }
  int orow0 = blockIdx.x * 64 + w * 16 + (lane >> 4) * 4;
  #pragma unroll
  for (int hh = 0; hh < H; ++hh) {
    float ps[4] = {}, pd[4] = {};
    #pragma unroll
    for (int c4 = 0; c4 < 4; ++c4) {
      int cf = hh * 4 + c4;
      #pragma unroll
      for (int i = 0; i < 4; ++i) {
        ps[i] += acc[cf][i] * ws_[cf];
        pd[i] += acc[cf][i] * wd_[cf];
      }
    }
    #pragma unroll
    for (int off = 1; off < 16; off <<= 1)
      #pragma unroll
      for (int i = 0; i < 4; ++i) {
        ps[i] += __shfl_xor(ps[i], off);
        pd[i] += __shfl_xor(pd[i], off);
      }
    if ((lane & 15) == 0)
      #pragma unroll
      for (int i = 0; i < 4; ++i) {
        int r = orow0 + i;
        if (r < M) {
          aS[(size_t)r * H + hh] = ps[i];
          aD[(size_t)r * H + hh] = pd[i];
        }
      }
  }
  #pragma unroll
  for (int i = 0; i < 4; ++i) {
    int r = orow0 + i;
    if (r < M)
      #pragma unroll
      for (int cf = 0; cf < NN / 16; ++cf)
        hq[(size_t)r * NN + cf * 16 + (lane & 15)] = f2bf(acc[cf][i]);
  }
}

// ---------------------------------------------- raw-load typing for H=4 / H=2
template <int H> struct Raw;
template <> struct Raw<4> { using T = uint2; };
template <> struct Raw<2> { using T = unsigned int; };

template <int H>
__device__ __forceinline__ void unpack(typename Raw<H>::T q, float* v);
template <>
__device__ __forceinline__ void unpack<4>(uint2 q, float* v) {
  v[0] = bflo(q.x); v[1] = bfhi(q.x); v[2] = bflo(q.y); v[3] = bfhi(q.y);
}
template <>
__device__ __forceinline__ void unpack<2>(unsigned int q, float* v) {
  v[0] = bflo(q); v[1] = bfhi(q);
}

// -------------- edge-softmax + aggregate, 3-phase wave-local LDS staging.
// Phase 0a (lane-parallel): stage (j, e) to LDS, butterfly-max per head.
// Phase 0b (lane-parallel): w = exp(e-m) once per edge, butterfly-sum denom.
// Phase 1  (channel-parallel): lean gather loop - ds_read j,w + 8B load + H fmac.
// Chunked (CAP edges) with flash-style merge for unbounded degree.
template <int H, bool ELU, bool OBF>
__global__ __launch_bounds__(256) void k_aggr(
    const int* __restrict__ rowptr, const int* __restrict__ csr,
    const unsigned short* __restrict__ hq,
    const float* __restrict__ aS, const float* __restrict__ aD,
    const float* __restrict__ bias, void* __restrict__ outv) {
  constexpr int CAP = 256;
  constexpr int C = H * 64;
  __shared__ int   jls[4][CAP];
  __shared__ float wls[4][CAP * H];
  int n    = (int)((blockIdx.x * (size_t)blockDim.x + threadIdx.x) >> 6);
  int lane = threadIdx.x & 63;
  int wsl  = threadIdx.x >> 6;
  if (n >= N_NODES) return;
  int* jl  = jls[wsl];
  float* wl = wls[wsl];
  int hl = (lane * H) >> 6;  // head owning this lane's H channels

  float ad[H];
  #pragma unroll
  for (int h = 0; h < H; ++h) ad[h] = aD[(size_t)n * H + h];

  int lo = rowptr[n], deg = rowptr[n + 1] - lo;
  float m[H], s[H], acc[H];
  #pragma unroll
  for (int h = 0; h < H; ++h) { m[h] = -1e30f; s[h] = 0.f; acc[h] = 0.f; }

  for (int c0 = 0; c0 < deg; c0 += CAP) {
    int cl = deg - c0; if (cl > CAP) cl = CAP;
    // ---- phase 0a: stage j,e; chunk max
    float cmx[H];
    #pragma unroll
    for (int h = 0; h < H; ++h) cmx[h] = -1e30f;
    for (int kk = lane; kk < cl; kk += 64) {
      int j = csr[lo + c0 + kk];
      jl[kk] = j;
      float e[H];
      if constexpr (H == 4) {
        float4 a4 = *(const float4*)&aS[(size_t)j * 4];
        e[0] = a4.x; e[1] = a4.y; e[2] = a4.z; e[3] = a4.w;
      } else {
        float2 a2 = *(const float2*)&aS[(size_t)j * 2];
        e[0] = a2.x; e[1] = a2.y;
      }
      #pragma unroll
      for (int h = 0; h < H; ++h) {
        float v = e[h] + ad[h];
        v = v > 0.f ? v : 0.2f * v;
        e[h] = v;
        cmx[h] = fmaxf(cmx[h], v);
      }
      if constexpr (H == 4)
        *(float4*)&wl[kk * 4] = make_float4(e[0], e[1], e[2], e[3]);
      else
        *(float2*)&wl[kk * 2] = make_float2(e[0], e[1]);
    }
    #pragma unroll
    for (int off = 1; off < 64; off <<= 1)
      #pragma unroll
      for (int h = 0; h < H; ++h)
        cmx[h] = fmaxf(cmx[h], __shfl_xor(cmx[h], off));
    float nm[H], fac[H], cs[H];
    #pragma unroll
    for (int h = 0; h < H; ++h) {
      nm[h] = fmaxf(m[h], cmx[h]);
      fac[h] = __expf(m[h] - nm[h]);
      cs[h] = 0.f;
    }
    __builtin_amdgcn_wave_barrier();
    // ---- phase 0b: w = exp(e - nm), chunk denom
    for (int kk = lane; kk < cl; kk += 64) {
      float e[H];
      if constexpr (H == 4) {
        float4 t = *(const float4*)&wl[kk * 4];
        e[0] = t.x; e[1] = t.y; e[2] = t.z; e[3] = t.w;
      } else {
        float2 t = *(const float2*)&wl[kk * 2];
        e[0] = t.x; e[1] = t.y;
      }
      #pragma unroll
      for (int h = 0; h < H; ++h) {
        float w = __expf(e[h] - nm[h]);
        e[h] = w;
        cs[h] += w;
      }
      if constexpr (H == 4)
        *(float4*)&wl[kk * 4] = make_float4(e[0], e[1], e[2], e[3]);
      else
        *(float2*)&wl[kk * 2] = make_float2(e[0], e[1]);
    }
    #pragma unroll
    for (int off = 1; off < 64; off <<= 1)
      #pragma unroll
      for (int h = 0; h < H; ++h)
        cs[h] += __shfl_xor(cs[h], off);
    #pragma unroll
    for (int h = 0; h < H; ++h) {
      s[h] = s[h] * fac[h] + cs[h];
      m[h] = nm[h];
    }
    float facl = fac[hl];
    #pragma unroll
    for (int c = 0; c < H; ++c) acc[c] *= facl;
    __builtin_amdgcn_wave_barrier();
    // ---- phase 1: lean gather-accumulate
    #pragma unroll 2
    for (int k = 0; k < cl; ++k) {
      int j = jl[k];
      float wgt = wl[k * H + hl];
      typename Raw<H>::T u = *(const typename Raw<H>::T*)&hq[(size_t)j * C + lane * H];
      float hv[H];
      unpack<H>(u, hv);
      #pragma unroll
      for (int c = 0; c < H; ++c) acc[c] += wgt * hv[c];
    }
    __builtin_amdgcn_wave_barrier();
  }

  float inv = 1.f / s[hl];
  float o[H];
  #pragma unroll
  for (int c = 0; c < H; ++c) {
    float v = acc[c] * inv + bias[lane * H + c];
    if (ELU) v = v > 0.f ? v : __expf(v) - 1.f;
    o[c] = v;
  }
  size_t idx = (size_t)n * C + lane * H;
  if constexpr (OBF) {
    unsigned short* outp = (unsigned short*)outv;
    if constexpr (H == 4)
      *(ushort4*)&outp[idx] = make_ushort4(f2bf(o[0]), f2bf(o[1]), f2bf(o[2]), f2bf(o[3]));
    else
      *(unsigned int*)&outp[idx] = (unsigned int)f2bf(o[0]) | ((unsigned int)f2bf(o[1]) << 16);
  } else {
    float* outp = (float*)outv;
    if constexpr (H == 4)
      *(float4*)&outp[idx] = make_float4(o[0], o[1], o[2], o[3]);
    else
      *(float2*)&outp[idx] = make_float2(o[0], o[1]);
  }
}

// --------------------------------------------------------- layer-3 (C=2, H=1)
__global__ void k_proj3(const float* __restrict__ hin, const float* __restrict__ W3,
                        const float* __restrict__ s3, const float* __restrict__ d3,
                        float* __restrict__ h3, float* __restrict__ a3s,
                        float* __restrict__ a3d) {
  int n = blockIdx.x * blockDim.x + threadIdx.x;
  if (n >= N_NODES) return;
  float a0 = 0.f, a1 = 0.f;
  const float4* hp = (const float4*)(hin + (size_t)n * 128);
  #pragma unroll
  for (int q = 0; q < 32; ++q) {
    float4 v = hp[q];
    const float* w = W3 + q * 8;
    a0 += v.x * w[0] + v.y * w[2] + v.z * w[4] + v.w * w[6];
    a1 += v.x * w[1] + v.y * w[3] + v.z * w[5] + v.w * w[7];
  }
  h3[(size_t)n * 2]     = a0;
  h3[(size_t)n * 2 + 1] = a1;
  a3s[n] = a0 * s3[0] + a1 * s3[1];
  a3d[n] = a0 * d3[0] + a1 * d3[1];
}

__global__ void k_aggr3(const int* __restrict__ rowptr, const int* __restrict__ csr,
                        const float* __restrict__ h3, const float* __restrict__ a3s,
                        const float* __restrict__ a3d, const float* __restrict__ b3,
                        float* __restrict__ out) {
  int n = blockIdx.x * blockDim.x + threadIdx.x;
  if (n >= N_NODES) return;
  float adv = a3d[n];
  float m = -1e30f, s = 0.f, acc0 = 0.f, acc1 = 0.f;
  int lo = rowptr[n], hi = rowptr[n + 1];
  for (int k = lo; k < hi; ++k) {
    int j = csr[k];
    float e = a3s[j] + adv;
    e = e > 0.f ? e : 0.2f * e;
    float h0 = h3[(size_t)j * 2], h1 = h3[(size_t)j * 2 + 1];
    float nm = fmaxf(m, e);
    float sc = __expf(m - nm);
    float w  = __expf(e - nm);
    s = s * sc + w; acc0 = acc0 * sc + w * h0; acc1 = acc1 * sc + w * h1;
    m = nm;
  }
  float o0 = acc0 / s + b3[0];
  float o1 = acc1 / s + b3[1];
  float mx = fmaxf(o0, o1);
  float l  = logf(__expf(o0 - mx) + __expf(o1 - mx));
  out[(size_t)n * 2]     = o0 - mx - l;
  out[(size_t)n * 2 + 1] = o1 - mx - l;
}

// ---------------------------------------------------------------- launcher
extern "C" void kernel_launch(void* const* d_in, const int* in_sizes, int n_in,
                              void* d_out, int out_size, void* d_ws, size_t ws_size,
                              hipStream_t stream) {
  const float* x   = (const float*)d_in[0];
  const int*   ei  = (const int*)d_in[1];
  const float* W1  = (const float*)d_in[2];
  const float* as1 = (const float*)d_in[3];
  const float* ad1 = (const float*)d_in[4];
  const float* b1  = (const float*)d_in[5];
  const float* W2  = (const float*)d_in[6];
  const float* as2 = (const float*)d_in[7];
  const float* ad2 = (const float*)d_in[8];
  const float* b2  = (const float*)d_in[9];
  const float* W3  = (const float*)d_in[10];
  const float* as3 = (const float*)d_in[11];
  const float* ad3 = (const float*)d_in[12];
  const float* b3  = (const float*)d_in[13];
  float* out = (float*)d_out;

  char* p = (char*)d_ws;
  auto alloc = [&](size_t bytes) -> char* {
    char* r = p; p += (bytes + 255) & ~(size_t)255; return r;
  };
  int*   cnt    = (int*)alloc((size_t)N_NODES * 4);
  int*   rowptr = (int*)alloc((size_t)(N_NODES + 1) * 4);
  int*   cursor = (int*)alloc((size_t)N_NODES * 4);
  int*   csr    = (int*)alloc((size_t)E_TOT * 4);
  int*   bsum   = (int*)alloc(256 * 4);
  int*   boff   = (int*)alloc(257 * 4);
  float* aS     = (float*)alloc((size_t)N_NODES * 4 * 4);
  float* aD     = (float*)alloc((size_t)N_NODES * 4 * 4);
  float* h3     = (float*)alloc((size_t)N_NODES * 2 * 4);
  float* a3s    = (float*)alloc((size_t)N_NODES * 4);
  float* a3d    = (float*)alloc((size_t)N_NODES * 4);
  unsigned short* xq  = (unsigned short*)alloc((size_t)N_NODES * 128 * 2);
  unsigned short* W1t = (unsigned short*)alloc((size_t)256 * 128 * 2);
  unsigned short* W2t = (unsigned short*)alloc((size_t)128 * 256 * 2);
  unsigned short* hq1 = (unsigned short*)alloc((size_t)N_NODES * 256 * 2);  // gemm1 out
  unsigned short* hBq = (unsigned short*)alloc((size_t)N_NODES * 256 * 2);  // aggr1 out
  unsigned short* hq2 = (unsigned short*)alloc((size_t)N_NODES * 128 * 2);  // gemm2 out
  float* h2o = (float*)hq1;  // aggr2 out (25.6 MB) aliases dead hq1

  // ---- input conversions (bf16)
  k_f2bf<<<(N_NODES * 128 / 4 + 255) / 256, 256, 0, stream>>>(x, xq, N_NODES * 128 / 4);
  k_wt<128, 256><<<(128 * 256 + 255) / 256, 256, 0, stream>>>(W1, W1t);
  k_wt<256, 128><<<(256 * 128 + 255) / 256, 256, 0, stream>>>(W2, W2t);

  // ---- CSR (reused by all three layers)
  hipMemsetAsync(cnt, 0, (size_t)N_NODES * 4, stream);
  k_hist<<<(E_TOT + 255) / 256, 256, 0, stream>>>(ei, cnt);
  k_bsum<<<SCAN_B, 256, 0, stream>>>(cnt, bsum);
  k_bscan<<<1, 256, 0, stream>>>(bsum, boff);
  k_rowptr<<<SCAN_B, 256, 0, stream>>>(cnt, boff, rowptr, cursor);
  k_scatter<<<(E_TOT + 255) / 256, 256, 0, stream>>>(ei, cursor, csr);

  const int GB = (N_NODES + 63) / 64;  // 782

  // ---- layer 1: 128 -> 4x64, concat, ELU
  k_gemm_mfma<128, 4><<<GB, 256, 0, stream>>>(
      xq, W1t, as1, ad1, hq1, aS, aD, N_NODES);
  k_aggr<4, true, true><<<(N_NODES + 3) / 4, 256, 0, stream>>>(
      rowptr, csr, hq1, aS, aD, b1, hBq);

  // ---- layer 2: 256 -> 2x64, concat, ELU
  k_gemm_mfma<256, 2><<<GB, 256, 0, stream>>>(
      hBq, W2t, as2, ad2, hq2, aS, aD, N_NODES);
  k_aggr<2, true, false><<<(N_NODES + 3) / 4, 256, 0, stream>>>(
      rowptr, csr, hq2, aS, aD, b2, h2o);

  // ---- layer 3: 128 -> 2, mean(1 head), bias, log_softmax
  k_proj3<<<(N_NODES + 255) / 256, 256, 0, stream>>>(h2o, W3, as3, ad3, h3, a3s, a3d);
  k_aggr3<<<(N_NODES + 255) / 256, 256, 0, stream>>>(rowptr, csr, h3, a3s, a3d, b3, out);
}